// Round 11
// baseline (213.119 us; speedup 1.0000x reference)
//
#include <hip/hip_runtime.h>
#include <hip/hip_bf16.h>
#include <math.h>

#define LVID 2048
#define LTXT 512
#define DMOD 512
#define LTOT 2560
#define LOG2_GAMMA (-0.15200309344504995f)   // log2(0.9)
#define LOG2E 1.4426950408889634f

typedef __bf16 bf16x8 __attribute__((ext_vector_type(8)));
typedef float f32x4 __attribute__((ext_vector_type(4)));

__device__ inline f32x4 mfma_bf16(bf16x8 a, bf16x8 b, f32x4 c) {
  return __builtin_amdgcn_mfma_f32_16x16x32_bf16(a, b, c, 0, 0, 0);
}

__device__ inline void gload_lds16(const void* g, void* l) {
  __builtin_amdgcn_global_load_lds(
      (const __attribute__((address_space(1))) void*)g,
      (__attribute__((address_space(3))) void*)l, 16, 0, 0);
}

union U8 { __hip_bfloat16 b[8]; uint4 u; };

// ======== fused prep (loss-partials + premask2 + weight cvt + vts zero) + LN1
__global__ __launch_bounds__(256) void k_prep_ln1(
    const float* __restrict__ lw, float* __restrict__ premask2,
    float* __restrict__ lossp, float* __restrict__ vts,
    const float* __restrict__ wq, const float* __restrict__ wk,
    const float* __restrict__ wv, const float* __restrict__ wo,
    const float* __restrict__ l1, const float* __restrict__ l2,
    __hip_bfloat16* __restrict__ dst,
    const float* __restrict__ src_vid, const float* __restrict__ src_txt,
    const float* __restrict__ w, const float* __restrict__ b,
    __hip_bfloat16* __restrict__ acat, float* __restrict__ srcA,
    float* __restrict__ posb) {
  int tid = threadIdx.x;
  int blk = blockIdx.x;
  if (blk < 64) vts[blk * 256 + tid] = 0.f;   // zero Vts (16384 f32) pre-QKV
  if (blk < 2048) {                    // ---- premask + loss partial (row = blk)
    __shared__ float red[256];
    int i = blk;
    int i0r = i & ~63;
    int tloCol = (i0r > 900) ? (((i0r - 900) >> 6) << 6) : 0;
    int idx0 = (blk * 256 + tid) * 8;
    int j0 = idx0 & 2047;
    float4 lv0 = *(const float4*)&lw[idx0];
    float4 lv1 = *(const float4*)&lw[idx0 + 4];
    float lvv[8] = {lv0.x, lv0.y, lv0.z, lv0.w, lv1.x, lv1.y, lv1.z, lv1.w};
    float pm[8];
    float s = 0.f;
#pragma unroll
    for (int e = 0; e < 8; e++) {
      int j = j0 + e;
      float sig = 1.f / (1.f + __expf(-lvv[e]));
      if (j != i) s += sig;
      float m = (j > i) ? 0.f
              : ((j == i) ? 1.f : exp2f((float)(i - j) * LOG2_GAMMA) * sig);
      pm[e] = m * LOG2E;
    }
    if (j0 >= tloCol && j0 < i0r + 64) {   // only the region attn reads
      *(float4*)&premask2[idx0]     = *(float4*)&pm[0];
      *(float4*)&premask2[idx0 + 4] = *(float4*)&pm[4];
    }
    red[tid] = s; __syncthreads();
    for (int st = 128; st > 0; st >>= 1) { if (tid < st) red[tid] += red[tid + st]; __syncthreads(); }
    if (tid == 0) lossp[blk] = red[0];
  } else if (blk < 4096) {             // ---- weight conversion
    int i4 = (blk - 2048) * 256 + tid;
    const float* sp; int base;
    if (i4 < 131072)      { if (i4 < 65536)  { sp = wq; base = 0; }      else { sp = wk; base = 65536; } }
    else if (i4 < 262144) { if (i4 < 196608) { sp = wv; base = 131072; } else { sp = wo; base = 196608; } }
    else if (i4 < 393216) { sp = l1; base = 262144; }
    else                  { sp = l2; base = 393216; }
    float4 v = ((const float4*)sp)[i4 - base];
    __hip_bfloat16 o[4] = {__float2bfloat16(v.x), __float2bfloat16(v.y),
                           __float2bfloat16(v.z), __float2bfloat16(v.w)};
    *(uint2*)(dst + (size_t)i4 * 4) = *(uint2*)o;
  } else {                             // ---- LN1 + xpos + sine pos
    int row = (blk - 4096) * 4 + (tid >> 6);
    int lane = tid & 63;
    const float* xs = (row < LVID) ? (src_vid + (size_t)row * DMOD)
                                   : (src_txt + (size_t)(row - LVID) * DMOD);
    float x[8];
    { float4 v0 = *(const float4*)&xs[lane * 8];
      float4 v1 = *(const float4*)&xs[lane * 8 + 4];
      x[0]=v0.x; x[1]=v0.y; x[2]=v0.z; x[3]=v0.w;
      x[4]=v1.x; x[5]=v1.y; x[6]=v1.z; x[7]=v1.w; }
    float s = 0.f;
#pragma unroll
    for (int i = 0; i < 8; i++) s += x[i];
#pragma unroll
    for (int st = 1; st < 64; st <<= 1) s += __shfl_xor(s, st, 64);
    float mu = s * (1.f / DMOD);
    float vs = 0.f;
#pragma unroll
    for (int i = 0; i < 8; i++) { float d = x[i] - mu; vs += d * d; }
#pragma unroll
    for (int st = 1; st < 64; st <<= 1) vs += __shfl_xor(vs, st, 64);
    float inv = rsqrtf(vs * (1.f / DMOD) + 1e-5f);
    float y[8];
    { float4 w0 = *(const float4*)&w[lane * 8];
      float4 w1 = *(const float4*)&w[lane * 8 + 4];
      float4 b0 = *(const float4*)&b[lane * 8];
      float4 b1 = *(const float4*)&b[lane * 8 + 4];
      float wv_[8] = {w0.x,w0.y,w0.z,w0.w,w1.x,w1.y,w1.z,w1.w};
      float bv_[8] = {b0.x,b0.y,b0.z,b0.w,b1.x,b1.y,b1.z,b1.w};
#pragma unroll
      for (int i = 0; i < 8; i++) y[i] = (x[i] - mu) * inv * wv_[i] + bv_[i]; }
    size_t base = (size_t)row * DMOD + lane * 8;
    if (row < LVID) {
      U8 pv;
#pragma unroll
      for (int i = 0; i < 8; i++) pv.b[i] = __float2bfloat16(y[i]);
      *(uint4*)&acat[(size_t)(4096 + row) * DMOD + lane * 8] = pv.u;
      float pq[8], pk[8];
      float l = (float)row;
#pragma unroll
      for (int p = 0; p < 4; p++) {
        int j = lane * 4 + p;
        float sj = (2.f * j + 204.8f) * (1.f / 716.8f);
        float scale = __powf(sj, l * (1.f / 512.f));
        float invfreq = __powf(10000.f, -(float)j * (1.f / 256.f));
        float sn, cs; __sincosf(l * invfreq, &sn, &cs);
        float cq = cs * scale, sq = sn * scale;
        pq[2*p]   = x[2*p] * cq - x[2*p+1] * sq;
        pq[2*p+1] = x[2*p+1] * cq + x[2*p] * sq;
        float isc = 1.f / scale;
        float ck = cs * isc, sk = sn * isc;
        pk[2*p]   = x[2*p] * ck - x[2*p+1] * sk;
        pk[2*p+1] = x[2*p+1] * ck + x[2*p] * sk;
      }
      *(float4*)&posb[base]     = *(float4*)&pq[0];
      *(float4*)&posb[base + 4] = *(float4*)&pq[4];
      U8 pqv, pkv;
#pragma unroll
      for (int i = 0; i < 8; i++) {
        pqv.b[i] = __float2bfloat16(y[i] + pq[i]);
        pkv.b[i] = __float2bfloat16(y[i] + pk[i]);
      }
      *(uint4*)&acat[(size_t)row * DMOD + lane * 8] = pqv.u;
      *(uint4*)&acat[(size_t)(2048 + row) * DMOD + lane * 8] = pkv.u;
    } else {
      int l = row - LVID;
      float xe = (float)(l + 1) * (6.28318530717958647692f / 512.000001f);
      float o8[8];
#pragma unroll
      for (int p = 0; p < 4; p++) {
        int j = lane * 4 + p;
        float dimt = __powf(10000.f, (float)j * (1.f / 256.f));
        float a = xe / dimt;
        o8[2*p]   = x[2*p]   + y[2*p]   + __sinf(a);
        o8[2*p+1] = x[2*p+1] + y[2*p+1] + __cosf(a);
      }
      *(float4*)&srcA[base]     = *(float4*)&o8[0];
      *(float4*)&srcA[base + 4] = *(float4*)&o8[4];
    }
  }
}

// ---------------- LN2: pure LN over srcA, bf16 out. Wave-per-row.
__global__ __launch_bounds__(256) void k_ln2(
    const float* __restrict__ srcA,
    const float* __restrict__ w, const float* __restrict__ b,
    __hip_bfloat16* __restrict__ obf) {
  int row = blockIdx.x * 4 + (threadIdx.x >> 6);
  int lane = threadIdx.x & 63;
  size_t base = (size_t)row * DMOD + lane * 8;
  float x[8];
  { float4 v0 = *(const float4*)&srcA[base];
    float4 v1 = *(const float4*)&srcA[base + 4];
    x[0]=v0.x; x[1]=v0.y; x[2]=v0.z; x[3]=v0.w;
    x[4]=v1.x; x[5]=v1.y; x[6]=v1.z; x[7]=v1.w; }
  float s = 0.f;
#pragma unroll
  for (int i = 0; i < 8; i++) s += x[i];
#pragma unroll
  for (int st = 1; st < 64; st <<= 1) s += __shfl_xor(s, st, 64);
  float mu = s * (1.f / DMOD);
  float vs = 0.f;
#pragma unroll
  for (int i = 0; i < 8; i++) { float d = x[i] - mu; vs += d * d; }
#pragma unroll
  for (int st = 1; st < 64; st <<= 1) vs += __shfl_xor(vs, st, 64);
  float inv = rsqrtf(vs * (1.f / DMOD) + 1e-5f);
  float4 w0 = *(const float4*)&w[lane * 8];
  float4 w1 = *(const float4*)&w[lane * 8 + 4];
  float4 b0 = *(const float4*)&b[lane * 8];
  float4 b1 = *(const float4*)&b[lane * 8 + 4];
  float wv_[8] = {w0.x,w0.y,w0.z,w0.w,w1.x,w1.y,w1.z,w1.w};
  float bv_[8] = {b0.x,b0.y,b0.z,b0.w,b1.x,b1.y,b1.z,b1.w};
  U8 o;
#pragma unroll
  for (int i = 0; i < 8; i++)
    o.b[i] = __float2bfloat16((x[i] - mu) * inv * wv_[i] + bv_[i]);
  *(uint4*)&obf[base] = o.u;
}

// ---------------- LN3: x = srcA + ffo0 + ffo1, f32 out; block 0 reduces loss
__global__ __launch_bounds__(256) void k_ln3(
    const float* __restrict__ srcA, const float* __restrict__ ffo0,
    const float* __restrict__ ffo1,
    const float* __restrict__ w, const float* __restrict__ b,
    float* __restrict__ o, const float* __restrict__ lossp) {
  if (blockIdx.x == 0 && threadIdx.x < 64) {
    float s = 0.f;
    for (int i = threadIdx.x; i < 2048; i += 64) s += lossp[i];
#pragma unroll
    for (int st = 1; st < 64; st <<= 1) s += __shfl_xor(s, st, 64);
    if (threadIdx.x == 0) o[1310720] = s * (1.f / 4194304.f);
  }
  int row = blockIdx.x * 4 + (threadIdx.x >> 6);
  int lane = threadIdx.x & 63;
  size_t base = (size_t)row * DMOD + lane * 8;
  float x[8];
  { float4 a0 = *(const float4*)&srcA[base];
    float4 a1 = *(const float4*)&srcA[base + 4];
    float4 f0 = *(const float4*)&ffo0[base];
    float4 f1 = *(const float4*)&ffo0[base + 4];
    float4 g0 = *(const float4*)&ffo1[base];
    float4 g1 = *(const float4*)&ffo1[base + 4];
    x[0]=a0.x+f0.x+g0.x; x[1]=a0.y+f0.y+g0.y; x[2]=a0.z+f0.z+g0.z; x[3]=a0.w+f0.w+g0.w;
    x[4]=a1.x+f1.x+g1.x; x[5]=a1.y+f1.y+g1.y; x[6]=a1.z+f1.z+g1.z; x[7]=a1.w+f1.w+g1.w; }
  float s = 0.f;
#pragma unroll
  for (int i = 0; i < 8; i++) s += x[i];
#pragma unroll
  for (int st = 1; st < 64; st <<= 1) s += __shfl_xor(s, st, 64);
  float mu = s * (1.f / DMOD);
  float vs = 0.f;
#pragma unroll
  for (int i = 0; i < 8; i++) { float d = x[i] - mu; vs += d * d; }
#pragma unroll
  for (int st = 1; st < 64; st <<= 1) vs += __shfl_xor(vs, st, 64);
  float inv = rsqrtf(vs * (1.f / DMOD) + 1e-5f);
  float4 w0 = *(const float4*)&w[lane * 8];
  float4 w1 = *(const float4*)&w[lane * 8 + 4];
  float4 b0 = *(const float4*)&b[lane * 8];
  float4 b1 = *(const float4*)&b[lane * 8 + 4];
  float wv_[8] = {w0.x,w0.y,w0.z,w0.w,w1.x,w1.y,w1.z,w1.w};
  float bv_[8] = {b0.x,b0.y,b0.z,b0.w,b1.x,b1.y,b1.z,b1.w};
  float y[8];
#pragma unroll
  for (int i = 0; i < 8; i++) y[i] = (x[i] - mu) * inv * wv_[i] + bv_[i];
  *(float4*)&o[base]     = *(float4*)&y[0];
  *(float4*)&o[base + 4] = *(float4*)&y[4];
}

// ======== bf16 MFMA GEMM v8: 64x64 tile, Keff=512 resident in 2 phases of 256,
// 64 KB static LDS (2 blocks/CU), THREE barriers total (vs 8 K-step drains).
// Staging keeps the wave-contiguous global_load_lds layout (16 rows x 32 k per
// 1 KB wave-instruction), identical banking to the proven gemm5.
// EPI: 2=f32+res1+res2, 3=QKV(q|k -> qkb; v -> vT + Vts), 4=bf16+GELU,
// 5=split-K partial f32 (blockIdx.z in {0,1}; K=1024 -> Keff=512).
template <int EPI>
__global__ __launch_bounds__(256) void k_gemm8(
    const __hip_bfloat16* __restrict__ A, const __hip_bfloat16* __restrict__ W0,
    const float* __restrict__ b0, const float* __restrict__ b1,
    const float* __restrict__ b2, void* __restrict__ Cv,
    const float* __restrict__ res1, const float* __restrict__ res2,
    __hip_bfloat16* __restrict__ vT, float* __restrict__ vts,
    int M, int N, int K) {
  __shared__ __hip_bfloat16 sA[16384];   // 8 chunks x [16 rows x 32 k] x 4 waves
  __shared__ __hip_bfloat16 sB[16384];
  int tid = threadIdx.x, lane = tid & 63, w = tid >> 6;
  int c16 = lane & 15, q4 = lane >> 4;
  int bm = blockIdx.y * 64, bn = blockIdx.x * 64;
  int seg = (EPI == 3) ? (bm >> 11) : 0;
  const __hip_bfloat16* Wp = (EPI == 3) ? (W0 + (size_t)seg * ((size_t)N * K)) : W0;
  int kb = (EPI == 5) ? (int)blockIdx.z * (K >> 1) : 0;
  int r0 = tid >> 2, cc0 = (tid & 3) * 8;
  const __hip_bfloat16* gA = A  + (size_t)(bm + r0) * K + kb + cc0;
  const __hip_bfloat16* gB = Wp + (size_t)(bn + r0) * K + kb + cc0;
  f32x4 acc[2][2];
  { f32x4 z = {0.f,0.f,0.f,0.f}; acc[0][0]=z; acc[0][1]=z; acc[1][0]=z; acc[1][1]=z; }
  int wm = w & 1, wn = w >> 1;
#pragma unroll
  for (int ph = 0; ph < 2; ph++) {
    if (ph) __syncthreads();           // phase-0 LDS reads complete before reuse
#pragma unroll
    for (int g = 0; g < 8; g++) {
      gload_lds16(gA + ph * 256 + g * 32, &sA[g * 2048 + (size_t)tid * 8]);
      gload_lds16(gB + ph * 256 + g * 32, &sB[g * 2048 + (size_t)tid * 8]);
    }
    __syncthreads();                   // staging drained (vmcnt(0) at barrier)
#pragma unroll
    for (int kk = 0; kk < 8; kk++) {
      bf16x8 a0  = *(const bf16x8*)&sA[kk*2048 + (wm*32 + c16) * 32 + q4*8];
      bf16x8 a1  = *(const bf16x8*)&sA[kk*2048 + (wm*32 + 16 + c16) * 32 + q4*8];
      bf16x8 bv0 = *(const bf16x8*)&sB[kk*2048 + (wn*32 + c16) * 32 + q4*8];
      bf16x8 bv1 = *(const bf16x8*)&sB[kk*2048 + (wn*32 + 16 + c16) * 32 + q4*8];
      acc[0][0] = mfma_bf16(a0, bv0, acc[0][0]);
      acc[0][1] = mfma_bf16(a0, bv1, acc[0][1]);
      acc[1][0] = mfma_bf16(a1, bv0, acc[1][0]);
      acc[1][1] = mfma_bf16(a1, bv1, acc[1][1]);
    }
  }
  float alpha = (EPI == 3 && seg == 0) ? 0.125f : 1.f;
  const float* bp = (EPI == 3) ? (seg == 0 ? b0 : (seg == 1 ? b1 : b2)) : b0;
  if (EPI == 3 && seg == 2) {
    // V segment: vT[d][j] via 8 B packed stores + Vts tile sums
    int tile = (bm & 2047) >> 6;
    float vsum[2] = {0.f, 0.f};
#pragma unroll
    for (int j = 0; j < 2; j++) {
      int n = bn + wn*32 + j*16 + c16;
      float bs = bp[n];
#pragma unroll
      for (int i = 0; i < 2; i++) {
        ushort4 u;
#pragma unroll
        for (int r = 0; r < 4; r++) {
          __hip_bfloat16 vb = __float2bfloat16(acc[i][j][r] + bs);
          ((__hip_bfloat16*)&u)[r] = vb;
          vsum[j] += __bfloat162float(vb);
        }
        int jj = (bm & 2047) + wm*32 + i*16 + q4*4;
        *(ushort4*)&vT[(size_t)n * 2048 + jj] = u;
      }
    }
#pragma unroll
    for (int j = 0; j < 2; j++) {
      float s2 = vsum[j];
      s2 += __shfl_xor(s2, 16, 64);
      s2 += __shfl_xor(s2, 32, 64);
      int n = bn + wn*32 + j*16 + c16;
      if (q4 == 0) atomicAdd(&vts[(size_t)(n >> 6) * 2048 + tile * 64 + (n & 63)], s2);
    }
    return;
  }
#pragma unroll
  for (int j = 0; j < 2; j++) {
    int n = bn + wn*32 + j*16 + c16;
    float bs = bp[n];
    if (EPI == 5 && blockIdx.z != 0) bs = 0.f;
#pragma unroll
    for (int i = 0; i < 2; i++) {
#pragma unroll
      for (int r = 0; r < 4; r++) {
        int m = bm + wm*32 + i*16 + q4*4 + r;
        float v = (acc[i][j][r] + bs) * alpha;
        if (EPI == 4) {
          v = 0.5f * v * (1.f + erff(v * 0.70710678118654752f));
          ((__hip_bfloat16*)Cv)[(size_t)m * N + n] = __float2bfloat16(v);
        } else if (EPI == 2) {
          size_t off = (size_t)m * N + n;
          ((float*)Cv)[off] = v + res1[off] + res2[off];
        } else if (EPI == 5) {
          ((float*)Cv)[(size_t)blockIdx.z * 1310720 + (size_t)m * N + n] = v;
        } else {  // EPI == 3, seg 0/1
          ((__hip_bfloat16*)Cv)[(size_t)(m & 2047) * 1024 + seg * 512 + n] = __float2bfloat16(v);
        }
      }
    }
  }
}

// ---------------- retention attention (R8): j-split x4, premask2 read
__global__ __launch_bounds__(256) void k_attn(
    const __hip_bfloat16* __restrict__ qkb,   // [2048][1024] = q|k
    const float* __restrict__ premask2,       // [2048][2048] incl log2e
    const __hip_bfloat16* __restrict__ vT,    // [512][2048]  (h*64+d, j)
    __hip_bfloat16* __restrict__ Obuf,        // [4][2048][512] unnorm partials
    float* __restrict__ ml) {                 // [4][8][2048][2]
  __shared__ __hip_bfloat16 sQ[64][72];
  __shared__ __hip_bfloat16 sK[2][64][72];
  __shared__ __hip_bfloat16 sVt[2][64][72];   // [d][j]
  __shared__ __hip_bfloat16 sP[64][72];       // [q][j]
  int i0 = blockIdx.x * 64, h = blockIdx.y, z = blockIdx.z;
  int tid = threadIdx.x, lane = tid & 63, w = tid >> 6;
  int c16 = lane & 15, q4 = lane >> 4;
  {  // stage Q
    int r = tid >> 2, c0 = (tid & 3) * 16;
    const __hip_bfloat16* g = qkb + (size_t)(i0 + r) * 1024 + h * 64 + c0;
    *(uint4*)&sQ[r][c0]     = *(const uint4*)g;
    *(uint4*)&sQ[r][c0 + 8] = *(const uint4*)(g + 8);
  }
  int thi = i0 >> 6;
  int tlo = (i0 > 900) ? ((i0 - 900) >> 6) : 0;
  int nt_ = thi - tlo + 1;
  int t0 = tlo + ((nt_ * z) >> 2);
  int t1 = tlo + ((nt_ * (z + 1)) >> 2) - 1;
  float rm = 0.f, rz = 0.f;       // per-lane stats for q-row = i0 + w*16 + c16
  f32x4 O[4];
  { f32x4 zz = {0.f,0.f,0.f,0.f}; O[0]=zz; O[1]=zz; O[2]=zz; O[3]=zz; }
  int kr = tid >> 2, kc = (tid & 3) * 16;
  uint4 pk0, pk1, pv0, pv1;
  if (t0 <= t1) {  // prefetch tile t0
    const __hip_bfloat16* gk = qkb + (size_t)(t0*64 + kr) * 1024 + 512 + h*64 + kc;
    pk0 = *(const uint4*)gk; pk1 = *(const uint4*)(gk + 8);
    const __hip_bfloat16* gv = vT + (size_t)(h*64 + kr) * 2048 + t0*64 + kc;
    pv0 = *(const uint4*)gv; pv1 = *(const uint4*)(gv + 8);
  }
  for (int t = t0; t <= t1; t++) {
    int buf = (t - t0) & 1;
    *(uint4*)&sK[buf][kr][kc]      = pk0;
    *(uint4*)&sK[buf][kr][kc + 8]  = pk1;
    *(uint4*)&sVt[buf][kr][kc]     = pv0;
    *(uint4*)&sVt[buf][kr][kc + 8] = pv1;
    __syncthreads();
    if (t < t1) {   // prefetch next tile, overlaps compute
      const __hip_bfloat16* gk = qkb + (size_t)((t+1)*64 + kr) * 1024 + 512 + h*64 + kc;
      pk0 = *(const uint4*)gk; pk1 = *(const uint4*)(gk + 8);
      const __hip_bfloat16* gv = vT + (size_t)(h*64 + kr) * 2048 + (t+1)*64 + kc;
      pv0 = *(const uint4*)gv; pv1 = *(const uint4*)(gv + 8);
    }
    // ---- S^T = K·Q^T : wave w owns q-cols w*16..+15
    bf16x8 bq0 = *(const bf16x8*)&sQ[w*16 + c16][q4*8];
    bf16x8 bq1 = *(const bf16x8*)&sQ[w*16 + c16][32 + q4*8];
    f32x4 St[4];
#pragma unroll
    for (int jt = 0; jt < 4; jt++) {
      f32x4 zz = {0.f,0.f,0.f,0.f};
      bf16x8 a0 = *(const bf16x8*)&sK[buf][jt*16 + c16][q4*8];
      bf16x8 a1 = *(const bf16x8*)&sK[buf][jt*16 + c16][32 + q4*8];
      zz = mfma_bf16(a0, bq0, zz);
      zz = mfma_bf16(a1, bq1, zz);
      St[jt] = zz;   // lane: q = w*16+c16, j = jt*16 + q4*4 + r
    }
    int qg = i0 + w*16 + c16;
    float lg[4][4];
    float tmax = -3.0e38f;
#pragma unroll
    for (int jt = 0; jt < 4; jt++) {
      float4 pm = *(const float4*)&premask2[(size_t)qg * 2048 + t*64 + jt*16 + q4*4];
      lg[jt][0] = St[jt][0] * pm.x; lg[jt][1] = St[jt][1] * pm.y;
      lg[jt][2] = St[jt][2] * pm.z; lg[jt][3] = St[jt][3] * pm.w;
#pragma unroll
      for (int r = 0; r < 4; r++) tmax = fmaxf(tmax, lg[jt][r]);
    }
    tmax = fmaxf(tmax, __shfl_xor(tmax, 16, 64));
    tmax = fmaxf(tmax, __shfl_xor(tmax, 32, 64));
    float mn = fmaxf(rm, tmax);
    float al = exp2f(rm - mn);
    rm = mn;
    float zp = 0.f;
#pragma unroll
    for (int jt = 0; jt < 4; jt++) {
      U8 e4;
      float e0 = exp2f(lg[jt][0] - rm), e1 = exp2f(lg[jt][1] - rm);
      float e2 = exp2f(lg[jt][2] - rm), e3 = exp2f(lg[jt][3] - rm);
      zp += e0 + e1 + e2 + e3;
      e4.b[0] = __float2bfloat16(e0); e4.b[1] = __float2bfloat16(e1);
      e4.b[2] = __float2bfloat16(e2); e4.b[3] = __float2bfloat16(e3);
      *(uint2*)&sP[w*16 + c16][jt*16 + q4*4] = *(uint2*)&e4.b[0];
    }
    zp += __shfl_xor(zp, 16, 64);
    zp += __shfl_xor(zp, 32, 64);
    rz = rz * al + zp;
    float alr[4];
#pragma unroll
    for (int r = 0; r < 4; r++) alr[r] = __shfl(al, q4*4 + r, 64);
#pragma unroll
    for (int dt = 0; dt < 4; dt++)
#pragma unroll
      for (int r = 0; r < 4; r++) O[dt][r] *= alr[r];
    bf16x8 ap0 = *(const bf16x8*)&sP[w*16 + c16][q4*8];
    bf16x8 ap1 = *(const bf16x8*)&sP[w*16 + c16][32 + q4*8];
#pragma unroll
    for (int dt = 0; dt < 4; dt++) {
      bf16x8 bv0 = *(const bf16x8*)&sVt[buf][dt*16 + c16][q4*8];
      bf16x8 bv1 = *(const bf16x8*)&sVt[buf][dt*16 + c16][32 + q4*8];
      O[dt] = mfma_bf16(ap0, bv0, O[dt]);
      O[dt] = mfma_bf16(ap1, bv1, O[dt]);
    }
  }
  // ---- write unnormalized partial O (C-layout rows) + per-row (m, l)
  __hip_bfloat16* ob = Obuf + (size_t)z * (2048 * 512);
#pragma unroll
  for (int dt = 0; dt < 4; dt++) {
    int d = dt*16 + c16;
#pragma unroll
    for (int r = 0; r < 4; r++)
      ob[(size_t)(i0 + w*16 + q4*4 + r) * DMOD + h*64 + d] = __float2bfloat16(O[dt][r]);
  }
  if (q4 == 0) {
    size_t mi = (((size_t)z * 8 + h) * 2048 + i0 + w*16 + c16) * 2;
    ml[mi] = rm; ml[mi + 1] = rz;
  }
}

// ---------------- combine: merge 4 partials + uniform-column term
__global__ __launch_bounds__(256) void k_comb(
    const __hip_bfloat16* __restrict__ Obuf, const float* __restrict__ ml,
    const float* __restrict__ vts,            // [8][32][64]
    __hip_bfloat16* __restrict__ outp) {      // vattb [2048][512]
  __shared__ float sV[32][64];
  __shared__ float sS[64];
  __shared__ float sC[64][6];
  int i0 = blockIdx.x * 64, h = blockIdx.y;
  int tid = threadIdx.x;
  int thi = i0 >> 6;
  int tlo = (i0 > 900) ? ((i0 - 900) >> 6) : 0;
  int n = thi - tlo + 1;
  float nu = (float)(2048 - 64 * n);
  {
    const float4* src = (const float4*)(vts + (size_t)h * 2048);
    ((float4*)&sV[0][0])[tid * 2]     = src[tid * 2];
    ((float4*)&sV[0][0])[tid * 2 + 1] = src[tid * 2 + 1];
  }
  __syncthreads();
  if (tid < 64) {
    float s = 0.f;
    for (int t = 0; t < 32; t++) if (t < tlo || t > thi) s += sV[t][tid];
    sS[tid] = s;
  } else if (tid < 128) {
    int r = tid - 64;
    int row = i0 + r;
    float m[4], l[4];
#pragma unroll
    for (int z = 0; z < 4; z++) {
      size_t mi = (((size_t)z * 8 + h) * 2048 + row) * 2;
      m[z] = ml[mi]; l[z] = ml[mi + 1];
    }
    float M = fmaxf(fmaxf(m[0], m[1]), fmaxf(m[2], m[3]));
    float au = exp2f(-M);
    float a[4], D = nu * au;
#pragma unroll
    for (int z = 0; z < 4; z++) { a[z] = exp2f(m[z] - M); D += l[z] * a[z]; }
    float dinv = 1.f / D;
#pragma unroll
    for (int z = 0; z < 4; z++) sC[r][z] = a[z] * dinv;
    sC[r][4] = au * dinv;
  }
  __syncthreads();
  int r = tid >> 2, dc = (tid & 3) * 16;
  size_t off = (size_t)(i0 + r) * DMOD + h * 64 + dc;
  float c[4];
#pragma unroll
  for (int z = 0; z < 4; z++) c[z] = sC[r][z];
  float cu = sC[r][4];
  float va[8], vb[8];
#pragma unroll
  for (int k = 0; k < 8; k++) { va[k] = sS[dc + k] * cu; vb[k] = sS[dc + 8 + k] * cu; }
#pragma unroll
  for (int z = 0; z < 4; z++) {
    U8 pa, pb;
    pa.u = *(const uint4*)&Obuf[(size_t)z * 2048 * 512 + off];
    pb.u = *(const uint4*)&Obuf[(size_t)z * 2048 * 512 + off + 8];
#pragma unroll
    for (int k = 0; k < 8; k++) {
      va[k] += __bfloat162float(pa.b[k]) * c[z];
      vb[k] += __bfloat162float(pb.b[k]) * c[z];
    }
  }
  U8 oa, obb;
#pragma unroll
  for (int k = 0; k < 8; k++) {
    oa.b[k]  = __float2bfloat16(va[k]);
    obb.b[k] = __float2bfloat16(vb[k]);
  }
  *(uint4*)&outp[off]     = oa.u;
  *(uint4*)&outp[off + 8] = obb.u;
}

// ----------------------------------------------------------------- launcher
extern "C" void kernel_launch(void* const* d_in, const int* in_sizes, int n_in,
                              void* d_out, int out_size, void* d_ws, size_t ws_size,
                              hipStream_t stream) {
  const float* src_vid = (const float*)d_in[0];
  const float* src_txt = (const float*)d_in[1];
  const float* ln1_w = (const float*)d_in[2];
  const float* ln1_b = (const float*)d_in[3];
  const float* wq = (const float*)d_in[4];
  const float* bq = (const float*)d_in[5];
  const float* wk = (const float*)d_in[6];
  const float* bk = (const float*)d_in[7];
  const float* wv = (const float*)d_in[8];
  const float* bv = (const float*)d_in[9];
  const float* wo = (const float*)d_in[10];
  const float* bo = (const float*)d_in[11];
  const float* lin1_w = (const float*)d_in[12];
  const float* lin1_b = (const float*)d_in[13];
  const float* lin2_w = (const float*)d_in[14];
  const float* lin2_b = (const float*)d_in[15];
  const float* ln2_w = (const float*)d_in[16];
  const float* ln2_b = (const float*)d_in[17];
  const float* ln3_w = (const float*)d_in[18];
  const float* ln3_b = (const float*)d_in[19];
  const float* lw = (const float*)d_in[20];
  float* out = (float*)d_out;

  const size_t MB = 1048576;
  char* wsb = (char*)d_ws;
  float* premask2       = (float*)(wsb + 0);             // 16 MiB
  __hip_bfloat16* wqb   = (__hip_bfloat16*)(wsb + 16*MB);// 4 MiB: wq|wk|wv|wo|l1|l2
  __hip_bfloat16* wob   = wqb + 786432;
  __hip_bfloat16* l1b   = wqb + 1048576;
  __hip_bfloat16* l2b   = wqb + 1572864;
  __hip_bfloat16* acat  = (__hip_bfloat16*)(wsb + 20*MB);// 6 MiB [6144][512]
  __hip_bfloat16* qkb   = (__hip_bfloat16*)(wsb + 26*MB);// 4 MiB [2048][1024]
  __hip_bfloat16* vTb   = (__hip_bfloat16*)(wsb + 30*MB);// 2 MiB [512][2048]
  __hip_bfloat16* Obuf  = (__hip_bfloat16*)(wsb + 32*MB);// 8 MiB [4][2048][512]
  float* mlb            = (float*)(wsb + 40*MB);         // 512 KiB
  float* vts            = (float*)(wsb + 41*MB);         // 64 KiB [8][32][64]
  __hip_bfloat16* vattb = (__hip_bfloat16*)(wsb + 42*MB);// 2 MiB
  float* srcA           = (float*)(wsb + 44*MB);         // 5 MiB
  float* posb           = (float*)(wsb + 49*MB);         // 4 MiB
  __hip_bfloat16* s2b   = (__hip_bfloat16*)(wsb + 54*MB);// 2.5 MiB
  __hip_bfloat16* hidb  = (__hip_bfloat16*)(wsb + 57*MB);// 5 MiB
  float* ffo0           = (float*)(wsb + 62*MB);         // 5 MiB
  float* ffo1           = (float*)(wsb + 67*MB);         // 5 MiB
  float* lossp          = (float*)(wsb + 72*MB);         // 8 KiB

  k_prep_ln1<<<4736, 256, 0, stream>>>(lw, premask2, lossp, vts,
      wq, wk, wv, wo, lin1_w, lin2_w, wqb,
      src_vid, src_txt, ln1_w, ln1_b, acat, srcA, posb);

  // QKV fused: q|k -> qkb, v -> vT + Vts. 768 blocks, 3-barrier K-resident.
  k_gemm8<3><<<dim3(8, 96), 256, 0, stream>>>(acat, wqb, bq, bk, bv,
      qkb, nullptr, nullptr, vTb, vts, 6144, 512, 512);
  // attention partials: 1024 blocks, balanced 4-way j-split, premask read
  k_attn<<<dim3(32, 8, 4), 256, 0, stream>>>(qkb, premask2, vTb, Obuf, mlb);
  k_comb<<<dim3(32, 8), 256, 0, stream>>>(Obuf, mlb, vts, vattb);
  // O-proj with fused residual: srcA(vid) = vatt@wo^T + bo + src_vid + posb
  k_gemm8<2><<<dim3(8, 32), 256, 0, stream>>>(vattb, wob, bo, nullptr, nullptr,
      srcA, src_vid, posb, nullptr, nullptr, 2048, 512, 512);
  k_ln2<<<640, 256, 0, stream>>>(srcA, ln2_w, ln2_b, s2b);
  // FFN1: 640 blocks
  k_gemm8<4><<<dim3(16, 40), 256, 0, stream>>>(s2b, l1b, lin1_b, nullptr, nullptr,
      hidb, nullptr, nullptr, nullptr, nullptr, 2560, 1024, 512);
  // FFN2: split-K x2 -> 640 blocks; Keff=512
  k_gemm8<5><<<dim3(8, 40, 2), 256, 0, stream>>>(hidb, l2b, lin2_b, nullptr, nullptr,
      ffo0, nullptr, nullptr, nullptr, nullptr, 2560, 512, 1024);
  k_ln3<<<640, 256, 0, stream>>>(srcA, ffo0, ffo1, ln3_w, ln3_b, out, lossp);
}

// Round 12
// 203.868 us; speedup vs baseline: 1.0454x; 1.0454x over previous
//
#include <hip/hip_runtime.h>
#include <hip/hip_bf16.h>
#include <math.h>

#define LVID 2048
#define LTXT 512
#define DMOD 512
#define LTOT 2560
#define LOG2_GAMMA (-0.15200309344504995f)   // log2(0.9)
#define LOG2E 1.4426950408889634f

typedef __bf16 bf16x8 __attribute__((ext_vector_type(8)));
typedef float f32x4 __attribute__((ext_vector_type(4)));

__device__ inline f32x4 mfma_bf16(bf16x8 a, bf16x8 b, f32x4 c) {
  return __builtin_amdgcn_mfma_f32_16x16x32_bf16(a, b, c, 0, 0, 0);
}

__device__ inline void gload_lds16(const void* g, void* l) {
  __builtin_amdgcn_global_load_lds(
      (const __attribute__((address_space(1))) void*)g,
      (__attribute__((address_space(3))) void*)l, 16, 0, 0);
}

union U8 { __hip_bfloat16 b[8]; uint4 u; };

// ======== fused prep (loss-partials + premask2 + weight cvt + vts zero) + LN1
// blocks [0,2048): premask+loss-partial  [2048,4096): weight cvt  [4096,4736): LN1
__global__ __launch_bounds__(256) void k_prep_ln1(
    const float* __restrict__ lw, float* __restrict__ premask2,
    float* __restrict__ lossp, float* __restrict__ vts,
    const float* __restrict__ wq, const float* __restrict__ wk,
    const float* __restrict__ wv, const float* __restrict__ wo,
    const float* __restrict__ l1, const float* __restrict__ l2,
    __hip_bfloat16* __restrict__ dst,
    const float* __restrict__ src_vid, const float* __restrict__ src_txt,
    const float* __restrict__ w, const float* __restrict__ b,
    __hip_bfloat16* __restrict__ acat, float* __restrict__ srcA,
    float* __restrict__ posb) {
  int tid = threadIdx.x;
  int blk = blockIdx.x;
  if (blk < 64) vts[blk * 256 + tid] = 0.f;   // zero Vts (16384 f32) pre-QKV
  if (blk < 2048) {                    // ---- premask + loss partial (row = blk)
    __shared__ float red[256];
    int i = blk;
    int i0r = i & ~63;
    int tloCol = (i0r > 900) ? (((i0r - 900) >> 6) << 6) : 0;
    int idx0 = (blk * 256 + tid) * 8;
    int j0 = idx0 & 2047;
    float4 lv0 = *(const float4*)&lw[idx0];
    float4 lv1 = *(const float4*)&lw[idx0 + 4];
    float lvv[8] = {lv0.x, lv0.y, lv0.z, lv0.w, lv1.x, lv1.y, lv1.z, lv1.w};
    float pm[8];
    float s = 0.f;
#pragma unroll
    for (int e = 0; e < 8; e++) {
      int j = j0 + e;
      float sig = 1.f / (1.f + __expf(-lvv[e]));
      if (j != i) s += sig;
      float m = (j > i) ? 0.f
              : ((j == i) ? 1.f : exp2f((float)(i - j) * LOG2_GAMMA) * sig);
      pm[e] = m * LOG2E;
    }
    if (j0 >= tloCol && j0 < i0r + 64) {   // only the region attn reads
      *(float4*)&premask2[idx0]     = *(float4*)&pm[0];
      *(float4*)&premask2[idx0 + 4] = *(float4*)&pm[4];
    }
    red[tid] = s; __syncthreads();
    for (int st = 128; st > 0; st >>= 1) { if (tid < st) red[tid] += red[tid + st]; __syncthreads(); }
    if (tid == 0) lossp[blk] = red[0];
  } else if (blk < 4096) {             // ---- weight conversion
    int i4 = (blk - 2048) * 256 + tid;
    const float* sp; int base;
    if (i4 < 131072)      { if (i4 < 65536)  { sp = wq; base = 0; }      else { sp = wk; base = 65536; } }
    else if (i4 < 262144) { if (i4 < 196608) { sp = wv; base = 131072; } else { sp = wo; base = 196608; } }
    else if (i4 < 393216) { sp = l1; base = 262144; }
    else                  { sp = l2; base = 393216; }
    float4 v = ((const float4*)sp)[i4 - base];
    __hip_bfloat16 o[4] = {__float2bfloat16(v.x), __float2bfloat16(v.y),
                           __float2bfloat16(v.z), __float2bfloat16(v.w)};
    *(uint2*)(dst + (size_t)i4 * 4) = *(uint2*)o;
  } else {                             // ---- LN1 + xpos + sine pos
    int row = (blk - 4096) * 4 + (tid >> 6);
    int lane = tid & 63;
    const float* xs = (row < LVID) ? (src_vid + (size_t)row * DMOD)
                                   : (src_txt + (size_t)(row - LVID) * DMOD);
    float x[8];
    { float4 v0 = *(const float4*)&xs[lane * 8];
      float4 v1 = *(const float4*)&xs[lane * 8 + 4];
      x[0]=v0.x; x[1]=v0.y; x[2]=v0.z; x[3]=v0.w;
      x[4]=v1.x; x[5]=v1.y; x[6]=v1.z; x[7]=v1.w; }
    float s = 0.f;
#pragma unroll
    for (int i = 0; i < 8; i++) s += x[i];
#pragma unroll
    for (int st = 1; st < 64; st <<= 1) s += __shfl_xor(s, st, 64);
    float mu = s * (1.f / DMOD);
    float vs = 0.f;
#pragma unroll
    for (int i = 0; i < 8; i++) { float d = x[i] - mu; vs += d * d; }
#pragma unroll
    for (int st = 1; st < 64; st <<= 1) vs += __shfl_xor(vs, st, 64);
    float inv = rsqrtf(vs * (1.f / DMOD) + 1e-5f);
    float y[8];
    { float4 w0 = *(const float4*)&w[lane * 8];
      float4 w1 = *(const float4*)&w[lane * 8 + 4];
      float4 b0 = *(const float4*)&b[lane * 8];
      float4 b1 = *(const float4*)&b[lane * 8 + 4];
      float wv_[8] = {w0.x,w0.y,w0.z,w0.w,w1.x,w1.y,w1.z,w1.w};
      float bv_[8] = {b0.x,b0.y,b0.z,b0.w,b1.x,b1.y,b1.z,b1.w};
#pragma unroll
      for (int i = 0; i < 8; i++) y[i] = (x[i] - mu) * inv * wv_[i] + bv_[i]; }
    size_t base = (size_t)row * DMOD + lane * 8;
    if (row < LVID) {
      U8 pv;
#pragma unroll
      for (int i = 0; i < 8; i++) pv.b[i] = __float2bfloat16(y[i]);
      *(uint4*)&acat[(size_t)(4096 + row) * DMOD + lane * 8] = pv.u;
      float pq[8], pk[8];
      float l = (float)row;
#pragma unroll
      for (int p = 0; p < 4; p++) {
        int j = lane * 4 + p;
        float sj = (2.f * j + 204.8f) * (1.f / 716.8f);
        float scale = __powf(sj, l * (1.f / 512.f));
        float invfreq = __powf(10000.f, -(float)j * (1.f / 256.f));
        float sn, cs; __sincosf(l * invfreq, &sn, &cs);
        float cq = cs * scale, sq = sn * scale;
        pq[2*p]   = x[2*p] * cq - x[2*p+1] * sq;
        pq[2*p+1] = x[2*p+1] * cq + x[2*p] * sq;
        float isc = 1.f / scale;
        float ck = cs * isc, sk = sn * isc;
        pk[2*p]   = x[2*p] * ck - x[2*p+1] * sk;
        pk[2*p+1] = x[2*p+1] * ck + x[2*p] * sk;
      }
      *(float4*)&posb[base]     = *(float4*)&pq[0];
      *(float4*)&posb[base + 4] = *(float4*)&pq[4];
      U8 pqv, pkv;
#pragma unroll
      for (int i = 0; i < 8; i++) {
        pqv.b[i] = __float2bfloat16(y[i] + pq[i]);
        pkv.b[i] = __float2bfloat16(y[i] + pk[i]);
      }
      *(uint4*)&acat[(size_t)row * DMOD + lane * 8] = pqv.u;
      *(uint4*)&acat[(size_t)(2048 + row) * DMOD + lane * 8] = pkv.u;
    } else {
      int l = row - LVID;
      float xe = (float)(l + 1) * (6.28318530717958647692f / 512.000001f);
      float o8[8];
#pragma unroll
      for (int p = 0; p < 4; p++) {
        int j = lane * 4 + p;
        float dimt = __powf(10000.f, (float)j * (1.f / 256.f));
        float a = xe / dimt;
        o8[2*p]   = x[2*p]   + y[2*p]   + __sinf(a);
        o8[2*p+1] = x[2*p+1] + y[2*p+1] + __cosf(a);
      }
      *(float4*)&srcA[base]     = *(float4*)&o8[0];
      *(float4*)&srcA[base + 4] = *(float4*)&o8[4];
    }
  }
}

// ---------------- LN2: pure LN over srcA, bf16 out. Wave-per-row.
__global__ __launch_bounds__(256) void k_ln2(
    const float* __restrict__ srcA,
    const float* __restrict__ w, const float* __restrict__ b,
    __hip_bfloat16* __restrict__ obf) {
  int row = blockIdx.x * 4 + (threadIdx.x >> 6);
  int lane = threadIdx.x & 63;
  size_t base = (size_t)row * DMOD + lane * 8;
  float x[8];
  { float4 v0 = *(const float4*)&srcA[base];
    float4 v1 = *(const float4*)&srcA[base + 4];
    x[0]=v0.x; x[1]=v0.y; x[2]=v0.z; x[3]=v0.w;
    x[4]=v1.x; x[5]=v1.y; x[6]=v1.z; x[7]=v1.w; }
  float s = 0.f;
#pragma unroll
  for (int i = 0; i < 8; i++) s += x[i];
#pragma unroll
  for (int st = 1; st < 64; st <<= 1) s += __shfl_xor(s, st, 64);
  float mu = s * (1.f / DMOD);
  float vs = 0.f;
#pragma unroll
  for (int i = 0; i < 8; i++) { float d = x[i] - mu; vs += d * d; }
#pragma unroll
  for (int st = 1; st < 64; st <<= 1) vs += __shfl_xor(vs, st, 64);
  float inv = rsqrtf(vs * (1.f / DMOD) + 1e-5f);
  float4 w0 = *(const float4*)&w[lane * 8];
  float4 w1 = *(const float4*)&w[lane * 8 + 4];
  float4 b0 = *(const float4*)&b[lane * 8];
  float4 b1 = *(const float4*)&b[lane * 8 + 4];
  float wv_[8] = {w0.x,w0.y,w0.z,w0.w,w1.x,w1.y,w1.z,w1.w};
  float bv_[8] = {b0.x,b0.y,b0.z,b0.w,b1.x,b1.y,b1.z,b1.w};
  U8 o;
#pragma unroll
  for (int i = 0; i < 8; i++)
    o.b[i] = __float2bfloat16((x[i] - mu) * inv * wv_[i] + bv_[i]);
  *(uint4*)&obf[base] = o.u;
}

// ---------------- LN3: x = srcA + ffo0 + ffo1, f32 out; block 0 reduces loss
__global__ __launch_bounds__(256) void k_ln3(
    const float* __restrict__ srcA, const float* __restrict__ ffo0,
    const float* __restrict__ ffo1,
    const float* __restrict__ w, const float* __restrict__ b,
    float* __restrict__ o, const float* __restrict__ lossp) {
  if (blockIdx.x == 0 && threadIdx.x < 64) {
    float s = 0.f;
    for (int i = threadIdx.x; i < 2048; i += 64) s += lossp[i];
#pragma unroll
    for (int st = 1; st < 64; st <<= 1) s += __shfl_xor(s, st, 64);
    if (threadIdx.x == 0) o[1310720] = s * (1.f / 4194304.f);
  }
  int row = blockIdx.x * 4 + (threadIdx.x >> 6);
  int lane = threadIdx.x & 63;
  size_t base = (size_t)row * DMOD + lane * 8;
  float x[8];
  { float4 a0 = *(const float4*)&srcA[base];
    float4 a1 = *(const float4*)&srcA[base + 4];
    float4 f0 = *(const float4*)&ffo0[base];
    float4 f1 = *(const float4*)&ffo0[base + 4];
    float4 g0 = *(const float4*)&ffo1[base];
    float4 g1 = *(const float4*)&ffo1[base + 4];
    x[0]=a0.x+f0.x+g0.x; x[1]=a0.y+f0.y+g0.y; x[2]=a0.z+f0.z+g0.z; x[3]=a0.w+f0.w+g0.w;
    x[4]=a1.x+f1.x+g1.x; x[5]=a1.y+f1.y+g1.y; x[6]=a1.z+f1.z+g1.z; x[7]=a1.w+f1.w+g1.w; }
  float s = 0.f;
#pragma unroll
  for (int i = 0; i < 8; i++) s += x[i];
#pragma unroll
  for (int st = 1; st < 64; st <<= 1) s += __shfl_xor(s, st, 64);
  float mu = s * (1.f / DMOD);
  float vs = 0.f;
#pragma unroll
  for (int i = 0; i < 8; i++) { float d = x[i] - mu; vs += d * d; }
#pragma unroll
  for (int st = 1; st < 64; st <<= 1) vs += __shfl_xor(vs, st, 64);
  float inv = rsqrtf(vs * (1.f / DMOD) + 1e-5f);
  float4 w0 = *(const float4*)&w[lane * 8];
  float4 w1 = *(const float4*)&w[lane * 8 + 4];
  float4 b0 = *(const float4*)&b[lane * 8];
  float4 b1 = *(const float4*)&b[lane * 8 + 4];
  float wv_[8] = {w0.x,w0.y,w0.z,w0.w,w1.x,w1.y,w1.z,w1.w};
  float bv_[8] = {b0.x,b0.y,b0.z,b0.w,b1.x,b1.y,b1.z,b1.w};
  float y[8];
#pragma unroll
  for (int i = 0; i < 8; i++) y[i] = (x[i] - mu) * inv * wv_[i] + bv_[i];
  *(float4*)&o[base]     = *(float4*)&y[0];
  *(float4*)&o[base + 4] = *(float4*)&y[4];
}

// ======== bf16 MFMA GEMM v5: 64x64 tile, BK=64 (2x32 half-tiles), 32 KB LDS
// dbuf, ONE barrier per 64-K step -> 8 MFMA/wave/step. [R8 config: best measured]
// EPI: 2=f32+res1+res2, 3=QKV(q|k -> qkb; v -> vT + Vts), 4=bf16+GELU,
// 5=split-K partial f32 (blockIdx.z in {0,1}).
template <int EPI>
__global__ __launch_bounds__(256) void k_gemm5(
    const __hip_bfloat16* __restrict__ A, const __hip_bfloat16* __restrict__ W0,
    const float* __restrict__ b0, const float* __restrict__ b1,
    const float* __restrict__ b2, void* __restrict__ Cv,
    const float* __restrict__ res1, const float* __restrict__ res2,
    __hip_bfloat16* __restrict__ vT, float* __restrict__ vts,
    int M, int N, int K) {
  __shared__ __hip_bfloat16 sA[2][4096];   // [buf][kc*2048 + row*32 + k]
  __shared__ __hip_bfloat16 sB[2][4096];
  int tid = threadIdx.x, lane = tid & 63, w = tid >> 6;
  int c16 = lane & 15, q4 = lane >> 4;
  int bm = blockIdx.y * 64, bn = blockIdx.x * 64;
  int seg = (EPI == 3) ? (bm >> 11) : 0;
  const __hip_bfloat16* Wp = (EPI == 3) ? (W0 + (size_t)seg * ((size_t)N * K)) : W0;
  int kb   = (EPI == 5) ? (int)blockIdx.z * (K >> 1) : 0;
  int Keff = (EPI == 5) ? (K >> 1) : K;
  int r0 = tid >> 2, cc0 = (tid & 3) * 8;
  const __hip_bfloat16* gA = A  + (size_t)(bm + r0) * K + kb + cc0;
  const __hip_bfloat16* gB = Wp + (size_t)(bn + r0) * K + kb + cc0;
  auto stage = [&](int buf, int k0) {
    gload_lds16(gA + k0,      &sA[buf][(size_t)tid * 8]);
    gload_lds16(gA + k0 + 32, &sA[buf][2048 + (size_t)tid * 8]);
    gload_lds16(gB + k0,      &sB[buf][(size_t)tid * 8]);
    gload_lds16(gB + k0 + 32, &sB[buf][2048 + (size_t)tid * 8]);
  };
  f32x4 acc[2][2];
  { f32x4 z = {0.f,0.f,0.f,0.f}; acc[0][0]=z; acc[0][1]=z; acc[1][0]=z; acc[1][1]=z; }
  int wm = w & 1, wn = w >> 1;
  const int S = Keff >> 6;
  stage(0, 0);
  for (int s = 0; s < S; s++) {
    __syncthreads();
    if (s + 1 < S) stage((s + 1) & 1, (s + 1) * 64);
    int bf = s & 1;
#pragma unroll
    for (int kc = 0; kc < 2; kc++) {
      bf16x8 a0  = *(const bf16x8*)&sA[bf][kc*2048 + (wm*32 + c16) * 32 + q4*8];
      bf16x8 a1  = *(const bf16x8*)&sA[bf][kc*2048 + (wm*32 + 16 + c16) * 32 + q4*8];
      bf16x8 bv0 = *(const bf16x8*)&sB[bf][kc*2048 + (wn*32 + c16) * 32 + q4*8];
      bf16x8 bv1 = *(const bf16x8*)&sB[bf][kc*2048 + (wn*32 + 16 + c16) * 32 + q4*8];
      acc[0][0] = mfma_bf16(a0, bv0, acc[0][0]);
      acc[0][1] = mfma_bf16(a0, bv1, acc[0][1]);
      acc[1][0] = mfma_bf16(a1, bv0, acc[1][0]);
      acc[1][1] = mfma_bf16(a1, bv1, acc[1][1]);
    }
  }
  float alpha = (EPI == 3 && seg == 0) ? 0.125f : 1.f;
  const float* bp = (EPI == 3) ? (seg == 0 ? b0 : (seg == 1 ? b1 : b2)) : b0;
  if (EPI == 3 && seg == 2) {
    // V segment: write vT[d_global][j] via 8 B packed stores + Vts tile sums
    int tile = (bm & 2047) >> 6;
    float vsum[2] = {0.f, 0.f};
#pragma unroll
    for (int j = 0; j < 2; j++) {
      int n = bn + wn*32 + j*16 + c16;
      float bs = bp[n];
#pragma unroll
      for (int i = 0; i < 2; i++) {
        ushort4 u;
#pragma unroll
        for (int r = 0; r < 4; r++) {
          __hip_bfloat16 vb = __float2bfloat16(acc[i][j][r] + bs);
          ((__hip_bfloat16*)&u)[r] = vb;
          vsum[j] += __bfloat162float(vb);
        }
        int jj = (bm & 2047) + wm*32 + i*16 + q4*4;
        *(ushort4*)&vT[(size_t)n * 2048 + jj] = u;
      }
    }
#pragma unroll
    for (int j = 0; j < 2; j++) {
      float s2 = vsum[j];
      s2 += __shfl_xor(s2, 16, 64);
      s2 += __shfl_xor(s2, 32, 64);
      int n = bn + wn*32 + j*16 + c16;
      if (q4 == 0) atomicAdd(&vts[(size_t)(n >> 6) * 2048 + tile * 64 + (n & 63)], s2);
    }
    return;
  }
#pragma unroll
  for (int j = 0; j < 2; j++) {
    int n = bn + wn*32 + j*16 + c16;
    float bs = bp[n];
    if (EPI == 5 && blockIdx.z != 0) bs = 0.f;
#pragma unroll
    for (int i = 0; i < 2; i++) {
#pragma unroll
      for (int r = 0; r < 4; r++) {
        int m = bm + wm*32 + i*16 + q4*4 + r;
        float v = (acc[i][j][r] + bs) * alpha;
        if (EPI == 4) {
          v = 0.5f * v * (1.f + erff(v * 0.70710678118654752f));
          ((__hip_bfloat16*)Cv)[(size_t)m * N + n] = __float2bfloat16(v);
        } else if (EPI == 2) {
          size_t off = (size_t)m * N + n;
          ((float*)Cv)[off] = v + res1[off] + res2[off];
        } else if (EPI == 5) {
          ((float*)Cv)[(size_t)blockIdx.z * 1310720 + (size_t)m * N + n] = v;
        } else {  // EPI == 3, seg 0/1
          ((__hip_bfloat16*)Cv)[(size_t)(m & 2047) * 1024 + seg * 512 + n] = __float2bfloat16(v);
        }
      }
    }
  }
}

// ---------------- retention attention (R8): j-split x4, premask2 read
__global__ __launch_bounds__(256) void k_attn(
    const __hip_bfloat16* __restrict__ qkb,   // [2048][1024] = q|k
    const float* __restrict__ premask2,       // [2048][2048] incl log2e
    const __hip_bfloat16* __restrict__ vT,    // [512][2048]  (h*64+d, j)
    __hip_bfloat16* __restrict__ Obuf,        // [4][2048][512] unnorm partials
    float* __restrict__ ml) {                 // [4][8][2048][2]
  __shared__ __hip_bfloat16 sQ[64][72];
  __shared__ __hip_bfloat16 sK[2][64][72];
  __shared__ __hip_bfloat16 sVt[2][64][72];   // [d][j]
  __shared__ __hip_bfloat16 sP[64][72];       // [q][j]
  int i0 = blockIdx.x * 64, h = blockIdx.y, z = blockIdx.z;
  int tid = threadIdx.x, lane = tid & 63, w = tid >> 6;
  int c16 = lane & 15, q4 = lane >> 4;
  {  // stage Q
    int r = tid >> 2, c0 = (tid & 3) * 16;
    const __hip_bfloat16* g = qkb + (size_t)(i0 + r) * 1024 + h * 64 + c0;
    *(uint4*)&sQ[r][c0]     = *(const uint4*)g;
    *(uint4*)&sQ[r][c0 + 8] = *(const uint4*)(g + 8);
  }
  int thi = i0 >> 6;
  int tlo = (i0 > 900) ? ((i0 - 900) >> 6) : 0;
  int nt_ = thi - tlo + 1;
  int t0 = tlo + ((nt_ * z) >> 2);
  int t1 = tlo + ((nt_ * (z + 1)) >> 2) - 1;
  float rm = 0.f, rz = 0.f;       // per-lane stats for q-row = i0 + w*16 + c16
  f32x4 O[4];
  { f32x4 zz = {0.f,0.f,0.f,0.f}; O[0]=zz; O[1]=zz; O[2]=zz; O[3]=zz; }
  int kr = tid >> 2, kc = (tid & 3) * 16;
  uint4 pk0, pk1, pv0, pv1;
  if (t0 <= t1) {  // prefetch tile t0
    const __hip_bfloat16* gk = qkb + (size_t)(t0*64 + kr) * 1024 + 512 + h*64 + kc;
    pk0 = *(const uint4*)gk; pk1 = *(const uint4*)(gk + 8);
    const __hip_bfloat16* gv = vT + (size_t)(h*64 + kr) * 2048 + t0*64 + kc;
    pv0 = *(const uint4*)gv; pv1 = *(const uint4*)(gv + 8);
  }
  for (int t = t0; t <= t1; t++) {
    int buf = (t - t0) & 1;
    *(uint4*)&sK[buf][kr][kc]      = pk0;
    *(uint4*)&sK[buf][kr][kc + 8]  = pk1;
    *(uint4*)&sVt[buf][kr][kc]     = pv0;
    *(uint4*)&sVt[buf][kr][kc + 8] = pv1;
    __syncthreads();
    if (t < t1) {   // prefetch next tile, overlaps compute
      const __hip_bfloat16* gk = qkb + (size_t)((t+1)*64 + kr) * 1024 + 512 + h*64 + kc;
      pk0 = *(const uint4*)gk; pk1 = *(const uint4*)(gk + 8);
      const __hip_bfloat16* gv = vT + (size_t)(h*64 + kr) * 2048 + (t+1)*64 + kc;
      pv0 = *(const uint4*)gv; pv1 = *(const uint4*)(gv + 8);
    }
    // ---- S^T = K·Q^T : wave w owns q-cols w*16..+15
    bf16x8 bq0 = *(const bf16x8*)&sQ[w*16 + c16][q4*8];
    bf16x8 bq1 = *(const bf16x8*)&sQ[w*16 + c16][32 + q4*8];
    f32x4 St[4];
#pragma unroll
    for (int jt = 0; jt < 4; jt++) {
      f32x4 zz = {0.f,0.f,0.f,0.f};
      bf16x8 a0 = *(const bf16x8*)&sK[buf][jt*16 + c16][q4*8];
      bf16x8 a1 = *(const bf16x8*)&sK[buf][jt*16 + c16][32 + q4*8];
      zz = mfma_bf16(a0, bq0, zz);
      zz = mfma_bf16(a1, bq1, zz);
      St[jt] = zz;   // lane: q = w*16+c16, j = jt*16 + q4*4 + r
    }
    int qg = i0 + w*16 + c16;
    float lg[4][4];
    float tmax = -3.0e38f;
#pragma unroll
    for (int jt = 0; jt < 4; jt++) {
      float4 pm = *(const float4*)&premask2[(size_t)qg * 2048 + t*64 + jt*16 + q4*4];
      lg[jt][0] = St[jt][0] * pm.x; lg[jt][1] = St[jt][1] * pm.y;
      lg[jt][2] = St[jt][2] * pm.z; lg[jt][3] = St[jt][3] * pm.w;
#pragma unroll
      for (int r = 0; r < 4; r++) tmax = fmaxf(tmax, lg[jt][r]);
    }
    tmax = fmaxf(tmax, __shfl_xor(tmax, 16, 64));
    tmax = fmaxf(tmax, __shfl_xor(tmax, 32, 64));
    float mn = fmaxf(rm, tmax);
    float al = exp2f(rm - mn);
    rm = mn;
    float zp = 0.f;
#pragma unroll
    for (int jt = 0; jt < 4; jt++) {
      U8 e4;
      float e0 = exp2f(lg[jt][0] - rm), e1 = exp2f(lg[jt][1] - rm);
      float e2 = exp2f(lg[jt][2] - rm), e3 = exp2f(lg[jt][3] - rm);
      zp += e0 + e1 + e2 + e3;
      e4.b[0] = __float2bfloat16(e0); e4.b[1] = __float2bfloat16(e1);
      e4.b[2] = __float2bfloat16(e2); e4.b[3] = __float2bfloat16(e3);
      *(uint2*)&sP[w*16 + c16][jt*16 + q4*4] = *(uint2*)&e4.b[0];
    }
    zp += __shfl_xor(zp, 16, 64);
    zp += __shfl_xor(zp, 32, 64);
    rz = rz * al + zp;
    float alr[4];
#pragma unroll
    for (int r = 0; r < 4; r++) alr[r] = __shfl(al, q4*4 + r, 64);
#pragma unroll
    for (int dt = 0; dt < 4; dt++)
#pragma unroll
      for (int r = 0; r < 4; r++) O[dt][r] *= alr[r];
    bf16x8 ap0 = *(const bf16x8*)&sP[w*16 + c16][q4*8];
    bf16x8 ap1 = *(const bf16x8*)&sP[w*16 + c16][32 + q4*8];
#pragma unroll
    for (int dt = 0; dt < 4; dt++) {
      bf16x8 bv0 = *(const bf16x8*)&sVt[buf][dt*16 + c16][q4*8];
      bf16x8 bv1 = *(const bf16x8*)&sVt[buf][dt*16 + c16][32 + q4*8];
      O[dt] = mfma_bf16(ap0, bv0, O[dt]);
      O[dt] = mfma_bf16(ap1, bv1, O[dt]);
    }
  }
  // ---- write unnormalized partial O (C-layout rows) + per-row (m, l)
  __hip_bfloat16* ob = Obuf + (size_t)z * (2048 * 512);
#pragma unroll
  for (int dt = 0; dt < 4; dt++) {
    int d = dt*16 + c16;
#pragma unroll
    for (int r = 0; r < 4; r++)
      ob[(size_t)(i0 + w*16 + q4*4 + r) * DMOD + h*64 + d] = __float2bfloat16(O[dt][r]);
  }
  if (q4 == 0) {
    size_t mi = (((size_t)z * 8 + h) * 2048 + i0 + w*16 + c16) * 2;
    ml[mi] = rm; ml[mi + 1] = rz;
  }
}

// ---------------- combine: merge 4 partials + uniform-column term
__global__ __launch_bounds__(256) void k_comb(
    const __hip_bfloat16* __restrict__ Obuf, const float* __restrict__ ml,
    const float* __restrict__ vts,            // [8][32][64]
    __hip_bfloat16* __restrict__ outp) {      // vattb [2048][512]
  __shared__ float sV[32][64];
  __shared__ float sS[64];
  __shared__ float sC[64][6];
  int i0 = blockIdx.x * 64, h = blockIdx.y;
  int tid = threadIdx.x;
  int thi = i0 >> 6;
  int tlo = (i0 > 900) ? ((i0 - 900) >> 6) : 0;
  int n = thi - tlo + 1;
  float nu = (float)(2048 - 64 * n);
  {
    const float4* src = (const float4*)(vts + (size_t)h * 2048);
    ((float4*)&sV[0][0])[tid * 2]     = src[tid * 2];
    ((float4*)&sV[0][0])[tid * 2 + 1] = src[tid * 2 + 1];
  }
  __syncthreads();
  if (tid < 64) {
    float s = 0.f;
    for (int t = 0; t < 32; t++) if (t < tlo || t > thi) s += sV[t][tid];
    sS[tid] = s;
  } else if (tid < 128) {
    int r = tid - 64;
    int row = i0 + r;
    float m[4], l[4];
#pragma unroll
    for (int z = 0; z < 4; z++) {
      size_t mi = (((size_t)z * 8 + h) * 2048 + row) * 2;
      m[z] = ml[mi]; l[z] = ml[mi + 1];
    }
    float M = fmaxf(fmaxf(m[0], m[1]), fmaxf(m[2], m[3]));
    float au = exp2f(-M);
    float a[4], D = nu * au;
#pragma unroll
    for (int z = 0; z < 4; z++) { a[z] = exp2f(m[z] - M); D += l[z] * a[z]; }
    float dinv = 1.f / D;
#pragma unroll
    for (int z = 0; z < 4; z++) sC[r][z] = a[z] * dinv;
    sC[r][4] = au * dinv;
  }
  __syncthreads();
  int r = tid >> 2, dc = (tid & 3) * 16;
  size_t off = (size_t)(i0 + r) * DMOD + h * 64 + dc;
  float c[4];
#pragma unroll
  for (int z = 0; z < 4; z++) c[z] = sC[r][z];
  float cu = sC[r][4];
  float va[8], vb[8];
#pragma unroll
  for (int k = 0; k < 8; k++) { va[k] = sS[dc + k] * cu; vb[k] = sS[dc + 8 + k] * cu; }
#pragma unroll
  for (int z = 0; z < 4; z++) {
    U8 pa, pb;
    pa.u = *(const uint4*)&Obuf[(size_t)z * 2048 * 512 + off];
    pb.u = *(const uint4*)&Obuf[(size_t)z * 2048 * 512 + off + 8];
#pragma unroll
    for (int k = 0; k < 8; k++) {
      va[k] += __bfloat162float(pa.b[k]) * c[z];
      vb[k] += __bfloat162float(pb.b[k]) * c[z];
    }
  }
  U8 oa, obb;
#pragma unroll
  for (int k = 0; k < 8; k++) {
    oa.b[k]  = __float2bfloat16(va[k]);
    obb.b[k] = __float2bfloat16(vb[k]);
  }
  *(uint4*)&outp[off]     = oa.u;
  *(uint4*)&outp[off + 8] = obb.u;
}

// ----------------------------------------------------------------- launcher
extern "C" void kernel_launch(void* const* d_in, const int* in_sizes, int n_in,
                              void* d_out, int out_size, void* d_ws, size_t ws_size,
                              hipStream_t stream) {
  const float* src_vid = (const float*)d_in[0];
  const float* src_txt = (const float*)d_in[1];
  const float* ln1_w = (const float*)d_in[2];
  const float* ln1_b = (const float*)d_in[3];
  const float* wq = (const float*)d_in[4];
  const float* bq = (const float*)d_in[5];
  const float* wk = (const float*)d_in[6];
  const float* bk = (const float*)d_in[7];
  const float* wv = (const float*)d_in[8];
  const float* bv = (const float*)d_in[9];
  const float* wo = (const float*)d_in[10];
  const float* bo = (const float*)d_in[11];
  const float* lin1_w = (const float*)d_in[12];
  const float* lin1_b = (const float*)d_in[13];
  const float* lin2_w = (const float*)d_in[14];
  const float* lin2_b = (const float*)d_in[15];
  const float* ln2_w = (const float*)d_in[16];
  const float* ln2_b = (const float*)d_in[17];
  const float* ln3_w = (const float*)d_in[18];
  const float* ln3_b = (const float*)d_in[19];
  const float* lw = (const float*)d_in[20];
  float* out = (float*)d_out;

  const size_t MB = 1048576;
  char* wsb = (char*)d_ws;
  float* premask2       = (float*)(wsb + 0);             // 16 MiB
  __hip_bfloat16* wqb   = (__hip_bfloat16*)(wsb + 16*MB);// 4 MiB: wq|wk|wv|wo|l1|l2
  __hip_bfloat16* wob   = wqb + 786432;
  __hip_bfloat16* l1b   = wqb + 1048576;
  __hip_bfloat16* l2b   = wqb + 1572864;
  __hip_bfloat16* acat  = (__hip_bfloat16*)(wsb + 20*MB);// 6 MiB [6144][512]
  __hip_bfloat16* qkb   = (__hip_bfloat16*)(wsb + 26*MB);// 4 MiB [2048][1024]
  __hip_bfloat16* vTb   = (__hip_bfloat16*)(wsb + 30*MB);// 2 MiB [512][2048]
  __hip_bfloat16* Obuf  = (__hip_bfloat16*)(wsb + 32*MB);// 8 MiB [4][2048][512]
  float* mlb            = (float*)(wsb + 40*MB);         // 512 KiB
  float* vts            = (float*)(wsb + 41*MB);         // 64 KiB [8][32][64]
  __hip_bfloat16* vattb = (__hip_bfloat16*)(wsb + 42*MB);// 2 MiB
  float* srcA           = (float*)(wsb + 44*MB);         // 5 MiB
  float* posb           = (float*)(wsb + 49*MB);         // 4 MiB
  __hip_bfloat16* s2b   = (__hip_bfloat16*)(wsb + 54*MB);// 2.5 MiB
  __hip_bfloat16* hidb  = (__hip_bfloat16*)(wsb + 57*MB);// 5 MiB
  float* ffo0           = (float*)(wsb + 62*MB);         // 5 MiB
  float* ffo1           = (float*)(wsb + 67*MB);         // 5 MiB
  float* lossp          = (float*)(wsb + 72*MB);         // 8 KiB

  k_prep_ln1<<<4736, 256, 0, stream>>>(lw, premask2, lossp, vts,
      wq, wk, wv, wo, lin1_w, lin2_w, wqb,
      src_vid, src_txt, ln1_w, ln1_b, acat, srcA, posb);

  // QKV fused: q|k -> qkb, v -> vT + Vts. 768 blocks, BK=64 (8 steps).
  k_gemm5<3><<<dim3(8, 96), 256, 0, stream>>>(acat, wqb, bq, bk, bv,
      qkb, nullptr, nullptr, vTb, vts, 6144, 512, 512);
  // attention partials: 1024 blocks, balanced 4-way j-split
  k_attn<<<dim3(32, 8, 4), 256, 0, stream>>>(qkb, premask2, vTb, Obuf, mlb);
  k_comb<<<dim3(32, 8), 256, 0, stream>>>(Obuf, mlb, vts, vattb);
  // O-proj with fused residual: srcA(vid) = vatt@wo^T + bo + src_vid + posb
  k_gemm5<2><<<dim3(8, 32), 256, 0, stream>>>(vattb, wob, bo, nullptr, nullptr,
      srcA, src_vid, posb, nullptr, nullptr, 2048, 512, 512);
  k_ln2<<<640, 256, 0, stream>>>(srcA, ln2_w, ln2_b, s2b);
  k_gemm5<4><<<dim3(16, 40), 256, 0, stream>>>(s2b, l1b, lin1_b, nullptr, nullptr,
      hidb, nullptr, nullptr, nullptr, nullptr, 2560, 1024, 512);
  k_gemm5<5><<<dim3(8, 40, 2), 256, 0, stream>>>(hidb, l2b, lin2_b, nullptr, nullptr,
      ffo0, nullptr, nullptr, nullptr, nullptr, 2560, 512, 1024);
  k_ln3<<<640, 256, 0, stream>>>(srcA, ffo0, ffo1, ln3_w, ln3_b, out, lossp);
}